// Round 1
// baseline (555.847 us; speedup 1.0000x reference)
//
#include <hip/hip_runtime.h>
#include <math.h>

namespace {
constexpr int Bx = 16;
constexpr int Cx = 256;
constexpr int Hx = 128;
constexpr int Wx = 128;
constexpr int PLANE = Hx * Wx;     // 16384 floats per (b,c) plane
constexpr int NPLANES = Bx * Cx;   // 4096
constexpr int SQ = 256;            // bottleneck dim = C*4*0.25
constexpr int C4 = 4 * Cx;         // 1024
}

// ---------------------------------------------------------------------------
// Kernel 1: per-(b,c) quadrant means.
// One block per plane; 256 threads; float4 loads (fully coalesced, 16B/lane).
// For float4 index v = tid + 256*i:
//   row  = v >> 5   (32 float4 per 128-col row)  -> top iff i < 8 (compile-time)
//   col4 = v & 31   -> left iff (tid>>4)&1 == 0  (fixed per thread)
// So each thread needs only 2 accumulators (top/bot for its column side).
// ---------------------------------------------------------------------------
__global__ __launch_bounds__(256) void k_qmeans(const float* __restrict__ t,
                                                float* __restrict__ means) {
    const int plane = blockIdx.x;           // b*Cx + c
    const int tid = threadIdx.x;
    const float4* tp = (const float4*)(t + (size_t)plane * PLANE);

    float sTop = 0.f, sBot = 0.f;
#pragma unroll
    for (int i = 0; i < 8; ++i) {
        float4 d = tp[tid + 256 * i];
        sTop += (d.x + d.y) + (d.z + d.w);
    }
#pragma unroll
    for (int i = 8; i < 16; ++i) {
        float4 d = tp[tid + 256 * i];
        sBot += (d.x + d.y) + (d.z + d.w);
    }

    // Butterfly over lane-xor masks {1,2,4,8,32}: combines exactly the 32
    // lanes of the wave that share bit 4 (the column-side bit).
#pragma unroll
    for (int m = 1; m <= 8; m <<= 1) {
        sTop += __shfl_xor(sTop, m);
        sBot += __shfl_xor(sBot, m);
    }
    sTop += __shfl_xor(sTop, 32);
    sBot += __shfl_xor(sBot, 32);

    __shared__ float red[4][4];             // [quadrant][wave]
    const int lane = tid & 63;
    const int wave = tid >> 6;
    const int qc = (tid >> 4) & 1;          // 0 = left half, 1 = right half
    if (lane == 0 || lane == 16) {
        red[qc][wave] = sTop;               // q0 / q1
        red[2 + qc][wave] = sBot;           // q2 / q3
    }
    __syncthreads();
    if (tid < 4) {
        const float s = red[tid][0] + red[tid][1] + red[tid][2] + red[tid][3];
        const int b = plane >> 8;
        const int c = plane & 255;
        // means layout: [b][q*Cx + c], quadrant order (00, 01, 10, 11)
        means[b * C4 + tid * Cx + c] = s * (1.f / (64.f * 64.f));
    }
}

// ---------------------------------------------------------------------------
// Kernel 2: fused MLP. One block per batch b.
//   z    = mish(means[b] @ w_reduce.T + b_reduce)      (256 outputs, 1/thread)
//   gate = sigmoid(z @ w_expand.T + b_expand)          (1024 outputs, 4/thread)
// means and z staged in LDS; weights (2 MiB total) come from L2/L3.
// ---------------------------------------------------------------------------
__global__ __launch_bounds__(256) void k_mlp(const float* __restrict__ means,
                                             const float* __restrict__ w_reduce,
                                             const float* __restrict__ b_reduce,
                                             const float* __restrict__ w_expand,
                                             const float* __restrict__ b_expand,
                                             float* __restrict__ gate) {
    const int b = blockIdx.x;
    const int tid = threadIdx.x;
    __shared__ __align__(16) float ms[C4];
    __shared__ __align__(16) float zs[SQ];

#pragma unroll
    for (int i = 0; i < 4; ++i)
        ms[tid + 256 * i] = means[b * C4 + tid + 256 * i];
    __syncthreads();

    {   // z[tid]
        float acc = b_reduce[tid];
        const float4* wr = (const float4*)(w_reduce + (size_t)tid * C4);
        const float4* m4 = (const float4*)ms;
#pragma unroll 8
        for (int k = 0; k < C4 / 4; ++k) {
            const float4 w = wr[k];
            const float4 m = m4[k];
            acc += m.x * w.x + m.y * w.y + m.z * w.z + m.w * w.w;
        }
        const float sp = (acc > 20.f) ? acc : log1pf(expf(acc));  // softplus
        zs[tid] = acc * tanhf(sp);                                 // mish
    }
    __syncthreads();

#pragma unroll
    for (int i = 0; i < 4; ++i) {
        const int j = tid + 256 * i;
        float acc = b_expand[j];
        const float4* we = (const float4*)(w_expand + (size_t)j * SQ);
        const float4* z4 = (const float4*)zs;
#pragma unroll 8
        for (int k = 0; k < SQ / 4; ++k) {
            const float4 w = we[k];
            const float4 z = z4[k];
            acc += z.x * w.x + z.y * w.y + z.z * w.z + z.w * w.w;
        }
        gate[b * C4 + j] = 1.f / (1.f + expf(-acc));
    }
}

// ---------------------------------------------------------------------------
// Kernel 3: apply gates. One block per plane; float4 read-scale-write.
// ---------------------------------------------------------------------------
__global__ __launch_bounds__(256) void k_apply(const float* __restrict__ t,
                                               const float* __restrict__ gate,
                                               float* __restrict__ out) {
    const int plane = blockIdx.x;
    const int tid = threadIdx.x;
    const int b = plane >> 8;
    const int c = plane & 255;

    const float g0 = gate[b * C4 + 0 * Cx + c];
    const float g1 = gate[b * C4 + 1 * Cx + c];
    const float g2 = gate[b * C4 + 2 * Cx + c];
    const float g3 = gate[b * C4 + 3 * Cx + c];
    const int qc = (tid >> 4) & 1;
    const float gTop = qc ? g1 : g0;
    const float gBot = qc ? g3 : g2;

    const float4* tp = (const float4*)(t + (size_t)plane * PLANE);
    float4* op = (float4*)((float*)out + (size_t)plane * PLANE);
#pragma unroll
    for (int i = 0; i < 16; ++i) {
        float4 d = tp[tid + 256 * i];
        const float g = (i < 8) ? gTop : gBot;
        d.x *= g; d.y *= g; d.z *= g; d.w *= g;
        op[tid + 256 * i] = d;
    }
}

extern "C" void kernel_launch(void* const* d_in, const int* in_sizes, int n_in,
                              void* d_out, int out_size, void* d_ws, size_t ws_size,
                              hipStream_t stream) {
    const float* t        = (const float*)d_in[0];
    const float* w_reduce = (const float*)d_in[1];
    const float* b_reduce = (const float*)d_in[2];
    const float* w_expand = (const float*)d_in[3];
    const float* b_expand = (const float*)d_in[4];
    float* out = (float*)d_out;

    float* means = (float*)d_ws;            // 16*1024 floats = 64 KiB
    float* gate  = means + Bx * C4;         // 16*1024 floats = 64 KiB

    k_qmeans<<<NPLANES, 256, 0, stream>>>(t, means);
    k_mlp<<<Bx, 256, 0, stream>>>(means, w_reduce, b_reduce, w_expand, b_expand, gate);
    k_apply<<<NPLANES, 256, 0, stream>>>(t, gate, out);
}